// Round 5
// baseline (275.523 us; speedup 1.0000x reference)
//
#include <hip/hip_runtime.h>
#include <hip/hip_bf16.h>
#include <cstdint>

typedef __bf16 bf16_t;
typedef __bf16 bf16x8 __attribute__((ext_vector_type(8)));
typedef __bf16 bf16x4 __attribute__((ext_vector_type(4)));
typedef __bf16 bf16x2 __attribute__((ext_vector_type(2)));
typedef float  f32x4  __attribute__((ext_vector_type(4)));
typedef float  f32x16 __attribute__((ext_vector_type(16)));
typedef unsigned uint4v __attribute__((ext_vector_type(4)));

#define AS1 __attribute__((address_space(1)))
#define AS3 __attribute__((address_space(3)))

static __device__ __forceinline__ void gld_lds16(const void* g, void* l) {
  __builtin_amdgcn_global_load_lds((AS1 void*)g, (AS3 void*)l, 16, 0, 0);
}

static __device__ __forceinline__ unsigned pk2(float a, float b) {
  bf16x2 v; v[0] = (bf16_t)a; v[1] = (bf16_t)b;
  return __builtin_bit_cast(unsigned, v);
}

static __device__ __forceinline__ bf16x8 cat44(bf16x4 a, bf16x4 b) {
  bf16x8 r;
  r[0] = a[0]; r[1] = a[1]; r[2] = a[2]; r[3] = a[3];
  r[4] = b[0]; r[5] = b[1]; r[6] = b[2]; r[7] = b[3];
  return r;
}

// ---------------- convert / transpose ----------------

__global__ __launch_bounds__(256) void convert_f32_bf16(const float* __restrict__ in,
                                                        bf16_t* __restrict__ out, int n4) {
  int i = blockIdx.x * 256 + threadIdx.x;
  if (i < n4) {
    float4 v = ((const float4*)in)[i];
    bf16x4 o;
    o[0] = (bf16_t)v.x; o[1] = (bf16_t)v.y; o[2] = (bf16_t)v.z; o[3] = (bf16_t)v.w;
    *(bf16x4*)(out + (size_t)i * 4) = o;
  }
}

__global__ __launch_bounds__(256) void transpose_w(const float* __restrict__ in,
                                                   bf16_t* __restrict__ out, int K, int N) {
  __shared__ float tile[32][33];
  const int t = threadIdx.x, c = t & 31, r0 = t >> 5;
  const int bx = blockIdx.x, by = blockIdx.y;
#pragma unroll
  for (int i = 0; i < 4; ++i) {
    int r = r0 + i * 8;
    tile[r][c] = in[(size_t)(by * 32 + r) * N + bx * 32 + c];
  }
  __syncthreads();
#pragma unroll
  for (int i = 0; i < 4; ++i) {
    int r = r0 + i * 8;
    out[(size_t)(bx * 32 + r) * K + by * 32 + c] = (bf16_t)tile[c][r];
  }
}

// ---------------- 128x128 bf16 GEMM core ----------------
template <int KDIM>
static __device__ __forceinline__ void gemm128_compute(const bf16_t* __restrict__ A,
                                                       const bf16_t* __restrict__ Bt,
                                                       bf16_t* lA, bf16_t* lB,
                                                       f32x4 acc[4][4]) {
  const int t = threadIdx.x;
  const int lr = t & 15, g = (t >> 4) & 3;
  const int w = t >> 6, wr = w >> 1, wc = w & 1;
  const int bm = blockIdx.x, bn = blockIdx.y;

  for (int kt = 0; kt < KDIM; kt += 32) {
    __syncthreads();
#pragma unroll
    for (int c2 = 0; c2 < 2; ++c2) {
      const int idx = c2 * 256 + t;
      const int row = idx >> 2, cb = idx & 3;
      const int ldsoff = ((t & 192) + c2 * 256) * 8;
      gld_lds16(A  + (size_t)(bm * 128 + row) * KDIM + kt + cb * 8, lA + ldsoff);
      gld_lds16(Bt + (size_t)(bn * 128 + row) * KDIM + kt + cb * 8, lB + ldsoff);
    }
    __syncthreads();
    bf16x8 af[4], bv[4];
#pragma unroll
    for (int mi = 0; mi < 4; ++mi)
      af[mi] = *(const bf16x8*)(lA + (wr * 64 + mi * 16 + lr) * 32 + g * 8);
#pragma unroll
    for (int ni = 0; ni < 4; ++ni)
      bv[ni] = *(const bf16x8*)(lB + (wc * 64 + ni * 16 + lr) * 32 + g * 8);
#pragma unroll
    for (int mi = 0; mi < 4; ++mi)
#pragma unroll
      for (int ni = 0; ni < 4; ++ni)
        acc[mi][ni] = __builtin_amdgcn_mfma_f32_16x16x32_bf16(af[mi], bv[ni], acc[mi][ni], 0, 0, 0);
  }
}

__global__ __launch_bounds__(256) void gemm_qkv_k(const bf16_t* __restrict__ xb,
                                                  const bf16_t* __restrict__ wt,
                                                  bf16_t* __restrict__ Qo,
                                                  bf16_t* __restrict__ Ko,
                                                  bf16_t* __restrict__ Vto) {
  __shared__ bf16_t lA[128 * 32], lB[128 * 32];
  f32x4 acc[4][4] = {};
  gemm128_compute<1024>(xb, wt, lA, lB, acc);
  const int t = threadIdx.x, lr = t & 15, g = (t >> 4) & 3, w = t >> 6, wr = w >> 1, wc = w & 1;
  const int row0 = blockIdx.x * 128 + wr * 64, col0 = blockIdx.y * 128 + wc * 64;
#pragma unroll
  for (int mi = 0; mi < 4; ++mi) {
    const int row = row0 + mi * 16 + g * 4;
    const int b = row >> 11, s = row & 2047;
#pragma unroll
    for (int ni = 0; ni < 4; ++ni) {
      const int col = col0 + ni * 16 + lr;
      const int t3 = col >> 10, rem = col & 1023, h = rem >> 6, d = rem & 63;
      const int bh = b * 16 + h;
#pragma unroll
      for (int r = 0; r < 4; ++r) {
        const bf16_t v = (bf16_t)acc[mi][ni][r];
        if (t3 == 0)      Qo[((size_t)bh * 2048 + s + r) * 64 + d] = v;
        else if (t3 == 1) Ko[((size_t)bh * 2048 + s + r) * 64 + d] = v;
        else              Vto[((size_t)bh * 64 + d) * 2048 + s + r] = v;
      }
    }
  }
}

__global__ __launch_bounds__(256) void gemm_o_k(const bf16_t* __restrict__ attn,
                                                const bf16_t* __restrict__ wot,
                                                float* __restrict__ out) {
  __shared__ bf16_t lA[128 * 32], lB[128 * 32];
  f32x4 acc[4][4] = {};
  gemm128_compute<1024>(attn, wot, lA, lB, acc);
  const int t = threadIdx.x, lr = t & 15, g = (t >> 4) & 3, w = t >> 6, wr = w >> 1, wc = w & 1;
  const int row0 = blockIdx.x * 128 + wr * 64, col0 = blockIdx.y * 128 + wc * 64;
#pragma unroll
  for (int mi = 0; mi < 4; ++mi) {
    const int row = row0 + mi * 16 + g * 4;
#pragma unroll
    for (int ni = 0; ni < 4; ++ni) {
      const int col = col0 + ni * 16 + lr;
#pragma unroll
      for (int r = 0; r < 4; ++r)
        out[(size_t)(row + r) * 1024 + col] = acc[mi][ni][r];
    }
  }
}

// ---------------- flash attention: pipelined, optional KV-split ----------------
// PART=true : grid (16, 32, 2); each block does kv range [z*1024, z*1024+1024);
//             writes unnormalized Opart (f32 [sp][bh][2048][64]) + m/ls.
// PART=false: grid (16, 32); full kv; normalize + write Ao (bf16) directly.
// Lane (ql=l&31, hi=l>>5) holds s[r] = S[q=ql][kv=crow(r,hi)],
// crow(r,hi) = (r&3) + 8*(r>>2) + 4*hi. V loaded in crow order; P packed
// lane-locally (zero cross-lane) — PV internal k-map cancels.
template <bool PART>
__global__ __launch_bounds__(256, 3) void attn_k2(const bf16_t* __restrict__ Q,
                                                  const bf16_t* __restrict__ K,
                                                  const bf16_t* __restrict__ Vt,
                                                  float* __restrict__ Opart,
                                                  float* __restrict__ mpart,
                                                  float* __restrict__ lpart,
                                                  bf16_t* __restrict__ Ao) {
  __shared__ __align__(16) float obuf[4][32 * 64];  // 32 KB
  const int t = threadIdx.x, w = t >> 6, l = t & 63;
  const int ql = l & 31, hi = l >> 5;
  const int bh = blockIdx.y, b = bh >> 4, h = bh & 15;
  const int sp = PART ? blockIdx.z : 0;
  const int kvbase = sp * 1024;
  const int NT = PART ? 32 : 64;
  const bf16_t* Qb = Q + (size_t)bh * 2048 * 64;
  const bf16_t* Kb = K + (size_t)bh * 2048 * 64 + (size_t)kvbase * 64;
  const bf16_t* Vb = Vt + (size_t)bh * 64 * 2048 + kvbase;
  const int q0 = blockIdx.x * 128 + w * 32;
  const float cs = 0.18033688011112042f;  // log2(e)/sqrt(64)

  const bf16_t* qp = Qb + (size_t)(q0 + ql) * 64 + hi * 8;
  const bf16x8 qf0 = *(const bf16x8*)(qp);
  const bf16x8 qf1 = *(const bf16x8*)(qp + 16);
  const bf16x8 qf2 = *(const bf16x8*)(qp + 32);
  const bf16x8 qf3 = *(const bf16x8*)(qp + 48);

  const bf16_t* kq = Kb + (size_t)ql * 64 + hi * 8;
  const bf16_t* vrow0 = Vb + (size_t)ql * 2048 + hi * 4;   // d = ql
  const bf16_t* vrow1 = vrow0 + 32 * 2048;                 // d = 32 + ql

  f32x16 ot0 = {}, ot1 = {};
  float m = -1e30f, ls = 0.0f;

  // softmax + PV for one tile (s: scores, va/vb: crow-ordered V frags)
  auto tile_sm_pv = [&](const f32x16& s, const bf16x4 va[4], const bf16x4 vb[4]) {
    // tree max over 16 local kv
    float x0 = fmaxf(s[0], s[1]),  x1 = fmaxf(s[2], s[3]);
    float x2 = fmaxf(s[4], s[5]),  x3 = fmaxf(s[6], s[7]);
    float x4 = fmaxf(s[8], s[9]),  x5 = fmaxf(s[10], s[11]);
    float x6 = fmaxf(s[12], s[13]), x7 = fmaxf(s[14], s[15]);
    float y0 = fmaxf(x0, x1), y1 = fmaxf(x2, x3), y2 = fmaxf(x4, x5), y3 = fmaxf(x6, x7);
    float pm = fmaxf(fmaxf(y0, y1), fmaxf(y2, y3));
    pm = fmaxf(pm, __shfl_xor(pm, 32));
    const float cand = pm * cs;
    if (__any(cand - m > 8.0f)) {   // defer-max: rarely taken
      const float mn = fmaxf(m, cand);
      const float al = exp2f(m - mn);
      m = mn;
      ls *= al;
#pragma unroll
      for (int r = 0; r < 16; ++r) { ot0[r] *= al; ot1[r] *= al; }
    }
    float p[16];
#pragma unroll
    for (int r = 0; r < 16; ++r) p[r] = exp2f(fmaf(s[r], cs, -m));
    float a0 = (p[0] + p[1]) + (p[2] + p[3]);
    float a1 = (p[4] + p[5]) + (p[6] + p[7]);
    float a2 = (p[8] + p[9]) + (p[10] + p[11]);
    float a3 = (p[12] + p[13]) + (p[14] + p[15]);
    float rs = (a0 + a1) + (a2 + a3);
    ls += rs + __shfl_xor(rs, 32);

    unsigned w0 = pk2(p[0],  p[1]),  w1 = pk2(p[2],  p[3]);
    unsigned w2 = pk2(p[4],  p[5]),  w3 = pk2(p[6],  p[7]);
    unsigned w4 = pk2(p[8],  p[9]),  w5 = pk2(p[10], p[11]);
    unsigned w6 = pk2(p[12], p[13]), w7 = pk2(p[14], p[15]);
    uint4v u0 = {w0, w1, w2, w3};
    uint4v u1 = {w4, w5, w6, w7};
    bf16x8 pf0 = __builtin_bit_cast(bf16x8, u0);
    bf16x8 pf1 = __builtin_bit_cast(bf16x8, u1);

    ot0 = __builtin_amdgcn_mfma_f32_32x32x16_bf16(cat44(va[0], va[1]), pf0, ot0, 0, 0, 0);
    ot0 = __builtin_amdgcn_mfma_f32_32x32x16_bf16(cat44(va[2], va[3]), pf1, ot0, 0, 0, 0);
    ot1 = __builtin_amdgcn_mfma_f32_32x32x16_bf16(cat44(vb[0], vb[1]), pf0, ot1, 0, 0, 0);
    ot1 = __builtin_amdgcn_mfma_f32_32x32x16_bf16(cat44(vb[2], vb[3]), pf1, ot1, 0, 0, 0);
  };

  // prologue: K tile 0 -> scores; K tile 1 into kf
  bf16x8 kf0 = *(const bf16x8*)(kq);
  bf16x8 kf1 = *(const bf16x8*)(kq + 16);
  bf16x8 kf2 = *(const bf16x8*)(kq + 32);
  bf16x8 kf3 = *(const bf16x8*)(kq + 48);
  f32x16 scur = {};
  scur = __builtin_amdgcn_mfma_f32_32x32x16_bf16(kf0, qf0, scur, 0, 0, 0);
  scur = __builtin_amdgcn_mfma_f32_32x32x16_bf16(kf1, qf1, scur, 0, 0, 0);
  scur = __builtin_amdgcn_mfma_f32_32x32x16_bf16(kf2, qf2, scur, 0, 0, 0);
  scur = __builtin_amdgcn_mfma_f32_32x32x16_bf16(kf3, qf3, scur, 0, 0, 0);
  {
    const bf16_t* kn = kq + (size_t)32 * 64;
    kf0 = *(const bf16x8*)(kn);
    kf1 = *(const bf16x8*)(kn + 16);
    kf2 = *(const bf16x8*)(kn + 32);
    kf3 = *(const bf16x8*)(kn + 48);
  }

  for (int jt = 0; jt < NT - 1; ++jt) {
    const int kv0 = jt * 32;
    // V for current tile (consumed ~200cy later, after softmax)
    bf16x4 va[4], vb[4];
    va[0] = *(const bf16x4*)(vrow0 + kv0);
    va[1] = *(const bf16x4*)(vrow0 + kv0 + 8);
    va[2] = *(const bf16x4*)(vrow0 + kv0 + 16);
    va[3] = *(const bf16x4*)(vrow0 + kv0 + 24);
    vb[0] = *(const bf16x4*)(vrow1 + kv0);
    vb[1] = *(const bf16x4*)(vrow1 + kv0 + 8);
    vb[2] = *(const bf16x4*)(vrow1 + kv0 + 16);
    vb[3] = *(const bf16x4*)(vrow1 + kv0 + 24);

    // next-tile QK^T (MFMA pipe) — independent of this tile's softmax (VALU)
    f32x16 snx = {};
    snx = __builtin_amdgcn_mfma_f32_32x32x16_bf16(kf0, qf0, snx, 0, 0, 0);
    snx = __builtin_amdgcn_mfma_f32_32x32x16_bf16(kf1, qf1, snx, 0, 0, 0);
    snx = __builtin_amdgcn_mfma_f32_32x32x16_bf16(kf2, qf2, snx, 0, 0, 0);
    snx = __builtin_amdgcn_mfma_f32_32x32x16_bf16(kf3, qf3, snx, 0, 0, 0);
    // prefetch K for jt+2 (clamped)
    {
      const int kv2 = (jt + 2 < NT) ? (jt + 2) * 32 : (NT - 1) * 32;
      const bf16_t* kn = kq + (size_t)kv2 * 64;
      kf0 = *(const bf16x8*)(kn);
      kf1 = *(const bf16x8*)(kn + 16);
      kf2 = *(const bf16x8*)(kn + 32);
      kf3 = *(const bf16x8*)(kn + 48);
    }

    tile_sm_pv(scur, va, vb);
    scur = snx;
  }
  {  // last tile
    const int kv0 = (NT - 1) * 32;
    bf16x4 va[4], vb[4];
    va[0] = *(const bf16x4*)(vrow0 + kv0);
    va[1] = *(const bf16x4*)(vrow0 + kv0 + 8);
    va[2] = *(const bf16x4*)(vrow0 + kv0 + 16);
    va[3] = *(const bf16x4*)(vrow0 + kv0 + 24);
    vb[0] = *(const bf16x4*)(vrow1 + kv0);
    vb[1] = *(const bf16x4*)(vrow1 + kv0 + 8);
    vb[2] = *(const bf16x4*)(vrow1 + kv0 + 16);
    vb[3] = *(const bf16x4*)(vrow1 + kv0 + 24);
    tile_sm_pv(scur, va, vb);
  }

  if constexpr (PART) {
    // epilogue: raw ot -> [q][64] f32 via XOR-swizzled LDS, coalesced writes
    float* ob = &obuf[w][0];
#pragma unroll
    for (int rg = 0; rg < 4; ++rg) {
      const int d0 = rg * 8 + hi * 4;
      f32x4 v0 = {ot0[4 * rg + 0], ot0[4 * rg + 1], ot0[4 * rg + 2], ot0[4 * rg + 3]};
      f32x4 v1 = {ot1[4 * rg + 0], ot1[4 * rg + 1], ot1[4 * rg + 2], ot1[4 * rg + 3]};
      *(f32x4*)((char*)ob + ql * 256 + (((d0)      * 4) ^ ((ql & 15) << 4))) = v0;
      *(f32x4*)((char*)ob + ql * 256 + (((d0 + 32) * 4) ^ ((ql & 15) << 4))) = v1;
    }
    __syncthreads();
    const size_t rowbase = (size_t)(sp * 32 + bh) * 2048 + q0;
#pragma unroll
    for (int i = 0; i < 8; ++i) {
      const int c = i * 64 + l;
      const int qq = c >> 4, ch = c & 15;
      f32x4 vv = *(const f32x4*)((char*)ob + qq * 256 + ((ch * 16) ^ ((qq & 15) << 4)));
      *(f32x4*)(Opart + (rowbase + qq) * 64 + ch * 4) = vv;
    }
    if (hi == 0) {
      const size_t mi = rowbase + ql;
      mpart[mi] = m;
      lpart[mi] = ls;
    }
  } else {
    // normalize + bf16 transpose-store directly to Ao
    const float inv = 1.0f / ls;
    bf16_t* ob = (bf16_t*)&obuf[w][0];
#pragma unroll
    for (int rg = 0; rg < 4; ++rg) {
      const int d0 = rg * 8 + hi * 4;
      bf16x4 v0, v1;
#pragma unroll
      for (int j = 0; j < 4; ++j) {
        v0[j] = (bf16_t)(ot0[4 * rg + j] * inv);
        v1[j] = (bf16_t)(ot1[4 * rg + j] * inv);
      }
      *(bf16x4*)((char*)ob + ql * 128 + (((d0)      * 2) ^ ((ql & 7) << 4))) = v0;
      *(bf16x4*)((char*)ob + ql * 128 + (((d0 + 32) * 2) ^ ((ql & 7) << 4))) = v1;
    }
    __syncthreads();
#pragma unroll
    for (int i = 0; i < 4; ++i) {
      const int c = i * 64 + l;
      const int qq = c >> 3, ch = c & 7;
      bf16x8 vv = *(const bf16x8*)((char*)ob + qq * 128 + ((ch * 16) ^ ((qq & 7) << 4)));
      *(bf16x8*)(Ao + (size_t)(b * 2048 + q0 + qq) * 1024 + h * 64 + ch * 8) = vv;
    }
  }
}

// combine 2 partials -> normalized bf16 attn rows
__global__ __launch_bounds__(256) void attn_combine(const float* __restrict__ Opart,
                                                    const float* __restrict__ mpart,
                                                    const float* __restrict__ lpart,
                                                    bf16_t* __restrict__ Ao) {
  const int R = blockIdx.x * 4 + (threadIdx.x >> 6);
  const int d = threadIdx.x & 63;
  const int bh = R >> 11, q = R & 2047, b = bh >> 4, h = bh & 15;
  const size_t NP = (size_t)32 * 2048;
  const float m0 = mpart[R], m1 = mpart[NP + R];
  const float l0 = lpart[R], l1 = lpart[NP + R];
  const float M = fmaxf(m0, m1);
  const float w0 = exp2f(m0 - M), w1 = exp2f(m1 - M);
  const float inv = 1.0f / (w0 * l0 + w1 * l1);
  const float o0 = Opart[(size_t)R * 64 + d];
  const float o1 = Opart[(NP + R) * 64 + d];
  Ao[((size_t)b * 2048 + q) * 1024 + h * 64 + d] = (bf16_t)((w0 * o0 + w1 * o1) * inv);
}

// ---------------- launcher ----------------

extern "C" void kernel_launch(void* const* d_in, const int* in_sizes, int n_in,
                              void* d_out, int out_size, void* d_ws, size_t ws_size,
                              hipStream_t stream) {
  const float* x    = (const float*)d_in[0];  // [2,2048,1024]
  const float* wqkv = (const float*)d_in[1];  // [1024,3072]
  const float* wo   = (const float*)d_in[2];  // [1024,1024]
  float* out = (float*)d_out;

  char* ws = (char*)d_ws;
  bf16_t* xb    = (bf16_t*)(ws);                        // 8 MB  [4096][1024]
  bf16_t* wqkvT = (bf16_t*)(ws + (size_t)(8u  << 20));  // 6 MB  [3072][1024]
  bf16_t* woT   = (bf16_t*)(ws + (size_t)(14u << 20));  // 2 MB  [1024][1024]
  bf16_t* Qb    = (bf16_t*)(ws + (size_t)(16u << 20));  // 8 MB  [32][2048][64]
  bf16_t* Kb    = (bf16_t*)(ws + (size_t)(24u << 20));  // 8 MB
  bf16_t* Vtb   = (bf16_t*)(ws + (size_t)(32u << 20));  // 8 MB  [32][64][2048]
  bf16_t* attn  = (bf16_t*)(ws + (size_t)(40u << 20));  // 8 MB  [4096][1024]
  float*  Opart = (float*)(ws + (size_t)(48u << 20));   // 32 MB [2][32][2048][64]
  float*  mpart = (float*)(ws + (size_t)(80u << 20));   // 0.5 MB
  float*  lpart = (float*)(ws + (size_t)(80u << 20) + (512u << 10));  // 0.5 MB

  convert_f32_bf16<<<4096, 256, 0, stream>>>(x, xb, 4096 * 1024 / 4);
  transpose_w<<<dim3(96, 32), 256, 0, stream>>>(wqkv, wqkvT, 1024, 3072);
  transpose_w<<<dim3(32, 32), 256, 0, stream>>>(wo, woT, 1024, 1024);
  gemm_qkv_k<<<dim3(32, 24), 256, 0, stream>>>(xb, wqkvT, Qb, Kb, Vtb);

  if (ws_size >= ((size_t)81u << 20)) {
    attn_k2<true><<<dim3(16, 32, 2), 256, 0, stream>>>(Qb, Kb, Vtb, Opart, mpart, lpart, nullptr);
    attn_combine<<<16384, 256, 0, stream>>>(Opart, mpart, lpart, attn);
  } else {
    attn_k2<false><<<dim3(16, 32), 256, 0, stream>>>(Qb, Kb, Vtb, nullptr, nullptr, nullptr, attn);
  }

  gemm_o_k<<<dim3(32, 8), 256, 0, stream>>>(attn, woT, out);
}

// Round 6
// 150.319 us; speedup vs baseline: 1.8329x; 1.8329x over previous
//
#include <hip/hip_runtime.h>
#include <hip/hip_bf16.h>
#include <cstdint>

typedef __bf16 bf16_t;
typedef __bf16 bf16x8 __attribute__((ext_vector_type(8)));
typedef __bf16 bf16x4 __attribute__((ext_vector_type(4)));
typedef __bf16 bf16x2 __attribute__((ext_vector_type(2)));
typedef float  f32x4  __attribute__((ext_vector_type(4)));
typedef float  f32x16 __attribute__((ext_vector_type(16)));
typedef unsigned uint4v __attribute__((ext_vector_type(4)));

#define AS1 __attribute__((address_space(1)))
#define AS3 __attribute__((address_space(3)))

static __device__ __forceinline__ void gld_lds16(const void* g, void* l) {
  __builtin_amdgcn_global_load_lds((AS1 void*)g, (AS3 void*)l, 16, 0, 0);
}

static __device__ __forceinline__ unsigned pk2(float a, float b) {
  bf16x2 v; v[0] = (bf16_t)a; v[1] = (bf16_t)b;
  return __builtin_bit_cast(unsigned, v);
}

static __device__ __forceinline__ bf16x8 cat44(bf16x4 a, bf16x4 b) {
  bf16x8 r;
  r[0] = a[0]; r[1] = a[1]; r[2] = a[2]; r[3] = a[3];
  r[4] = b[0]; r[5] = b[1]; r[6] = b[2]; r[7] = b[3];
  return r;
}

// ---------------- convert / transpose ----------------

__global__ __launch_bounds__(256) void convert_f32_bf16(const float* __restrict__ in,
                                                        bf16_t* __restrict__ out, int n4) {
  int i = blockIdx.x * 256 + threadIdx.x;
  if (i < n4) {
    float4 v = ((const float4*)in)[i];
    bf16x4 o;
    o[0] = (bf16_t)v.x; o[1] = (bf16_t)v.y; o[2] = (bf16_t)v.z; o[3] = (bf16_t)v.w;
    *(bf16x4*)(out + (size_t)i * 4) = o;
  }
}

__global__ __launch_bounds__(256) void transpose_w(const float* __restrict__ in,
                                                   bf16_t* __restrict__ out, int K, int N) {
  __shared__ float tile[32][33];
  const int t = threadIdx.x, c = t & 31, r0 = t >> 5;
  const int bx = blockIdx.x, by = blockIdx.y;
#pragma unroll
  for (int i = 0; i < 4; ++i) {
    int r = r0 + i * 8;
    tile[r][c] = in[(size_t)(by * 32 + r) * N + bx * 32 + c];
  }
  __syncthreads();
#pragma unroll
  for (int i = 0; i < 4; ++i) {
    int r = r0 + i * 8;
    out[(size_t)(bx * 32 + r) * K + by * 32 + c] = (bf16_t)tile[c][r];
  }
}

// ---------------- 128x128 bf16 GEMM core ----------------
template <int KDIM>
static __device__ __forceinline__ void gemm128_compute(const bf16_t* __restrict__ A,
                                                       const bf16_t* __restrict__ Bt,
                                                       bf16_t* lA, bf16_t* lB,
                                                       f32x4 acc[4][4]) {
  const int t = threadIdx.x;
  const int lr = t & 15, g = (t >> 4) & 3;
  const int w = t >> 6, wr = w >> 1, wc = w & 1;
  const int bm = blockIdx.x, bn = blockIdx.y;

  for (int kt = 0; kt < KDIM; kt += 32) {
    __syncthreads();
#pragma unroll
    for (int c2 = 0; c2 < 2; ++c2) {
      const int idx = c2 * 256 + t;
      const int row = idx >> 2, cb = idx & 3;
      const int ldsoff = ((t & 192) + c2 * 256) * 8;
      gld_lds16(A  + (size_t)(bm * 128 + row) * KDIM + kt + cb * 8, lA + ldsoff);
      gld_lds16(Bt + (size_t)(bn * 128 + row) * KDIM + kt + cb * 8, lB + ldsoff);
    }
    __syncthreads();
    bf16x8 af[4], bv[4];
#pragma unroll
    for (int mi = 0; mi < 4; ++mi)
      af[mi] = *(const bf16x8*)(lA + (wr * 64 + mi * 16 + lr) * 32 + g * 8);
#pragma unroll
    for (int ni = 0; ni < 4; ++ni)
      bv[ni] = *(const bf16x8*)(lB + (wc * 64 + ni * 16 + lr) * 32 + g * 8);
#pragma unroll
    for (int mi = 0; mi < 4; ++mi)
#pragma unroll
      for (int ni = 0; ni < 4; ++ni)
        acc[mi][ni] = __builtin_amdgcn_mfma_f32_16x16x32_bf16(af[mi], bv[ni], acc[mi][ni], 0, 0, 0);
  }
}

__global__ __launch_bounds__(256) void gemm_qkv_k(const bf16_t* __restrict__ xb,
                                                  const bf16_t* __restrict__ wt,
                                                  bf16_t* __restrict__ Qo,
                                                  bf16_t* __restrict__ Ko,
                                                  bf16_t* __restrict__ Vto) {
  __shared__ bf16_t lA[128 * 32], lB[128 * 32];
  f32x4 acc[4][4] = {};
  gemm128_compute<1024>(xb, wt, lA, lB, acc);
  const int t = threadIdx.x, lr = t & 15, g = (t >> 4) & 3, w = t >> 6, wr = w >> 1, wc = w & 1;
  const int row0 = blockIdx.x * 128 + wr * 64, col0 = blockIdx.y * 128 + wc * 64;
#pragma unroll
  for (int mi = 0; mi < 4; ++mi) {
    const int row = row0 + mi * 16 + g * 4;
    const int b = row >> 11, s = row & 2047;
#pragma unroll
    for (int ni = 0; ni < 4; ++ni) {
      const int col = col0 + ni * 16 + lr;
      const int t3 = col >> 10, rem = col & 1023, h = rem >> 6, d = rem & 63;
      const int bh = b * 16 + h;
#pragma unroll
      for (int r = 0; r < 4; ++r) {
        const bf16_t v = (bf16_t)acc[mi][ni][r];
        if (t3 == 0)      Qo[((size_t)bh * 2048 + s + r) * 64 + d] = v;
        else if (t3 == 1) Ko[((size_t)bh * 2048 + s + r) * 64 + d] = v;
        else              Vto[((size_t)bh * 64 + d) * 2048 + s + r] = v;
      }
    }
  }
}

__global__ __launch_bounds__(256) void gemm_o_k(const bf16_t* __restrict__ attn,
                                                const bf16_t* __restrict__ wot,
                                                float* __restrict__ out) {
  __shared__ bf16_t lA[128 * 32], lB[128 * 32];
  f32x4 acc[4][4] = {};
  gemm128_compute<1024>(attn, wot, lA, lB, acc);
  const int t = threadIdx.x, lr = t & 15, g = (t >> 4) & 3, w = t >> 6, wr = w >> 1, wc = w & 1;
  const int row0 = blockIdx.x * 128 + wr * 64, col0 = blockIdx.y * 128 + wc * 64;
#pragma unroll
  for (int mi = 0; mi < 4; ++mi) {
    const int row = row0 + mi * 16 + g * 4;
#pragma unroll
    for (int ni = 0; ni < 4; ++ni) {
      const int col = col0 + ni * 16 + lr;
#pragma unroll
      for (int r = 0; r < 4; ++r)
        out[(size_t)(row + r) * 1024 + col] = acc[mi][ni][r];
    }
  }
}

// ---------------- flash attention: LDS-staged K/V, 2-phase pipeline ----------
// grid (16, 32): x = 128-row q block (4 waves * 32 q), y = bh.
// Q,K: [bh][2048][64] ; Vt: [bh][64][2048] ; Ao: [b][s][h*64+d]  (all bf16)
// Per tile (32 kv): K tile 4KB + V tile 4KB staged once per BLOCK via
// global_load_lds (coalesced 16B/lane, shared by all 4 waves), double-buffered.
// LDS K layout: addr(row, ch) = ch*512 + row*16   (ch = 16B d-chunk 0..7)
// LDS V layout: addr(d, vc)   = vc*1024 + d*16    (vc = 16B kv-chunk 0..3)
// Lane (ql=l&31, hi=l>>5) holds s[r] = S[q=ql][kv=crow(r,hi)],
// crow(r,hi) = (r&3) + 8*(r>>2) + 4*hi. V read in crow order; P packed
// lane-locally (zero cross-lane) — PV internal k-map cancels. (r4-verified math)
__global__ __launch_bounds__(256) void attn_k(const bf16_t* __restrict__ Q,
                                              const bf16_t* __restrict__ K,
                                              const bf16_t* __restrict__ Vt,
                                              bf16_t* __restrict__ Ao) {
  __shared__ __align__(16) char smem[16384];  // [2][4K] K | [2][4K] V; epilogue reuse
  const int t = threadIdx.x, w = t >> 6, l = t & 63;
  const int ql = l & 31, hi = l >> 5;
  const int bh = blockIdx.y, b = bh >> 4, h = bh & 15;
  const bf16_t* Qb = Q  + (size_t)bh * 2048 * 64;
  const bf16_t* Kb = K  + (size_t)bh * 2048 * 64;
  const bf16_t* Vb = Vt + (size_t)bh * 64 * 2048;
  const int q0 = blockIdx.x * 128 + w * 32;
  const float cs = 0.18033688011112042f;  // log2(e)/sqrt(64)

  // per-wave staging sources (wave w stages K chunk-pair w and V kv-chunk w)
  const bf16_t* ksrc = Kb + (size_t)(l & 31) * 64 + (w * 2 + (l >> 5)) * 8;
  const bf16_t* vsrc = Vb + (size_t)l * 2048 + w * 8;
  char* kdst0 = smem + w * 1024;           // + nb*4096
  char* vdst0 = smem + 8192 + w * 1024;    // + nb*4096

  // Q B-frags: lane holds Q[q0+ql][j*16 + hi*8 + e]
  const bf16_t* qp = Qb + (size_t)(q0 + ql) * 64 + hi * 8;
  const bf16x8 qf0 = *(const bf16x8*)(qp);
  const bf16x8 qf1 = *(const bf16x8*)(qp + 16);
  const bf16x8 qf2 = *(const bf16x8*)(qp + 32);
  const bf16x8 qf3 = *(const bf16x8*)(qp + 48);

  f32x16 ot0 = {}, ot1 = {};
  float m = -1e30f, ls = 0.0f;

  // prologue: stage tile 0 into buffer 0
  gld_lds16(ksrc, kdst0);
  gld_lds16(vsrc, vdst0);
  __syncthreads();  // drains vmcnt -> tile 0 resident

  for (int jt = 0; jt < 64; ++jt) {
    const int nb = jt & 1;
    // issue next-tile stage early (latency hides under this tile's compute)
    if (jt < 63) {
      const size_t kvn = (size_t)(jt + 1) * 32;
      gld_lds16(ksrc + kvn * 64, kdst0 + (nb ^ 1) * 4096);
      gld_lds16(vsrc + kvn,      vdst0 + (nb ^ 1) * 4096);
    }

    // fragment reads from current buffer
    const char* kb = smem + nb * 4096;
    const char* vb = smem + 8192 + nb * 4096;
    const bf16x8 kf0 = *(const bf16x8*)(kb + (hi + 0) * 512 + ql * 16);
    const bf16x8 kf1 = *(const bf16x8*)(kb + (hi + 2) * 512 + ql * 16);
    const bf16x8 kf2 = *(const bf16x8*)(kb + (hi + 4) * 512 + ql * 16);
    const bf16x8 kf3 = *(const bf16x8*)(kb + (hi + 6) * 512 + ql * 16);
    bf16x4 va[4], vbf[4];
#pragma unroll
    for (int i = 0; i < 4; ++i) {
      va[i]  = *(const bf16x4*)(vb + i * 1024 + ql * 16 + hi * 8);
      vbf[i] = *(const bf16x4*)(vb + i * 1024 + 512 + ql * 16 + hi * 8);
    }

    // S^T[kv][q] = K * Q^T (same (hi,e)->k map on both operands -> cancels)
    f32x16 s = {};
    s = __builtin_amdgcn_mfma_f32_32x32x16_bf16(kf0, qf0, s, 0, 0, 0);
    s = __builtin_amdgcn_mfma_f32_32x32x16_bf16(kf1, qf1, s, 0, 0, 0);
    s = __builtin_amdgcn_mfma_f32_32x32x16_bf16(kf2, qf2, s, 0, 0, 0);
    s = __builtin_amdgcn_mfma_f32_32x32x16_bf16(kf3, qf3, s, 0, 0, 0);

    // tree max over 16 local kv + partner half
    float x0 = fmaxf(s[0], s[1]),   x1 = fmaxf(s[2], s[3]);
    float x2 = fmaxf(s[4], s[5]),   x3 = fmaxf(s[6], s[7]);
    float x4 = fmaxf(s[8], s[9]),   x5 = fmaxf(s[10], s[11]);
    float x6 = fmaxf(s[12], s[13]), x7 = fmaxf(s[14], s[15]);
    float y0 = fmaxf(x0, x1), y1 = fmaxf(x2, x3), y2 = fmaxf(x4, x5), y3 = fmaxf(x6, x7);
    float pm = fmaxf(fmaxf(y0, y1), fmaxf(y2, y3));
    pm = fmaxf(pm, __shfl_xor(pm, 32));
    const float cand = pm * cs;
    if (__any(cand - m > 8.0f)) {   // defer-max: rarely taken
      const float mn = fmaxf(m, cand);
      const float al = exp2f(m - mn);
      m = mn;
      ls *= al;
#pragma unroll
      for (int r = 0; r < 16; ++r) { ot0[r] *= al; ot1[r] *= al; }
    }

    float p[16];
#pragma unroll
    for (int r = 0; r < 16; ++r) p[r] = exp2f(fmaf(s[r], cs, -m));
    float a0 = (p[0] + p[1]) + (p[2] + p[3]);
    float a1 = (p[4] + p[5]) + (p[6] + p[7]);
    float a2 = (p[8] + p[9]) + (p[10] + p[11]);
    float a3 = (p[12] + p[13]) + (p[14] + p[15]);
    float rs = (a0 + a1) + (a2 + a3);
    ls += rs + __shfl_xor(rs, 32);

    // pack P in crow order (lane-local; element e of pf0 <-> kv crow(e,hi))
    unsigned w0 = pk2(p[0],  p[1]),  w1 = pk2(p[2],  p[3]);
    unsigned w2 = pk2(p[4],  p[5]),  w3 = pk2(p[6],  p[7]);
    unsigned w4 = pk2(p[8],  p[9]),  w5 = pk2(p[10], p[11]);
    unsigned w6 = pk2(p[12], p[13]), w7 = pk2(p[14], p[15]);
    uint4v u0 = {w0, w1, w2, w3};
    uint4v u1 = {w4, w5, w6, w7};
    bf16x8 pf0 = __builtin_bit_cast(bf16x8, u0);
    bf16x8 pf1 = __builtin_bit_cast(bf16x8, u1);

    // O^T[d][q] += V^T * P^T
    ot0 = __builtin_amdgcn_mfma_f32_32x32x16_bf16(cat44(va[0],  va[1]),  pf0, ot0, 0, 0, 0);
    ot0 = __builtin_amdgcn_mfma_f32_32x32x16_bf16(cat44(va[2],  va[3]),  pf1, ot0, 0, 0, 0);
    ot1 = __builtin_amdgcn_mfma_f32_32x32x16_bf16(cat44(vbf[0], vbf[1]), pf0, ot1, 0, 0, 0);
    ot1 = __builtin_amdgcn_mfma_f32_32x32x16_bf16(cat44(vbf[2], vbf[3]), pf1, ot1, 0, 0, 0);

    // one barrier per tile: drains stage loads (vmcnt 0) + protects buffers
    __syncthreads();
  }

  // epilogue: normalize, transpose via XOR-swizzled LDS (reuse smem), store
  const float inv = 1.0f / ls;
  bf16_t* ob = (bf16_t*)(smem + w * 4096);
#pragma unroll
  for (int rg = 0; rg < 4; ++rg) {
    const int d0 = rg * 8 + hi * 4;
    bf16x4 v0, v1;
#pragma unroll
    for (int j = 0; j < 4; ++j) {
      v0[j] = (bf16_t)(ot0[4 * rg + j] * inv);
      v1[j] = (bf16_t)(ot1[4 * rg + j] * inv);
    }
    *(bf16x4*)((char*)ob + ql * 128 + (((d0)      * 2) ^ ((ql & 7) << 4))) = v0;
    *(bf16x4*)((char*)ob + ql * 128 + (((d0 + 32) * 2) ^ ((ql & 7) << 4))) = v1;
  }
  __syncthreads();
#pragma unroll
  for (int i = 0; i < 4; ++i) {
    const int c = i * 64 + l;
    const int qq = c >> 3, ch = c & 7;
    bf16x8 vv = *(const bf16x8*)((char*)ob + qq * 128 + ((ch * 16) ^ ((qq & 7) << 4)));
    *(bf16x8*)(Ao + (size_t)(b * 2048 + q0 + qq) * 1024 + h * 64 + ch * 8) = vv;
  }
}

// ---------------- launcher ----------------

extern "C" void kernel_launch(void* const* d_in, const int* in_sizes, int n_in,
                              void* d_out, int out_size, void* d_ws, size_t ws_size,
                              hipStream_t stream) {
  const float* x    = (const float*)d_in[0];  // [2,2048,1024]
  const float* wqkv = (const float*)d_in[1];  // [1024,3072]
  const float* wo   = (const float*)d_in[2];  // [1024,1024]
  float* out = (float*)d_out;

  char* ws = (char*)d_ws;
  bf16_t* xb    = (bf16_t*)(ws);                        // 8 MB  [4096][1024]
  bf16_t* wqkvT = (bf16_t*)(ws + (size_t)(8u  << 20));  // 6 MB  [3072][1024]
  bf16_t* woT   = (bf16_t*)(ws + (size_t)(14u << 20));  // 2 MB  [1024][1024]
  bf16_t* Qb    = (bf16_t*)(ws + (size_t)(16u << 20));  // 8 MB  [32][2048][64]
  bf16_t* Kb    = (bf16_t*)(ws + (size_t)(24u << 20));  // 8 MB
  bf16_t* Vtb   = (bf16_t*)(ws + (size_t)(32u << 20));  // 8 MB  [32][64][2048]
  bf16_t* attn  = (bf16_t*)(ws + (size_t)(40u << 20));  // 8 MB  [4096][1024]

  convert_f32_bf16<<<4096, 256, 0, stream>>>(x, xb, 4096 * 1024 / 4);
  transpose_w<<<dim3(96, 32), 256, 0, stream>>>(wqkv, wqkvT, 1024, 3072);
  transpose_w<<<dim3(32, 32), 256, 0, stream>>>(wo, woT, 1024, 1024);
  gemm_qkv_k<<<dim3(32, 24), 256, 0, stream>>>(xb, wqkvT, Qb, Kb, Vtb);
  attn_k<<<dim3(16, 32), 256, 0, stream>>>(Qb, Kb, Vtb, attn);
  gemm_o_k<<<dim3(32, 8), 256, 0, stream>>>(attn, woT, out);
}